// Round 5
// baseline (11316.224 us; speedup 1.0000x reference)
//
#include <hip/hip_runtime.h>
#include <hip/hip_bf16.h>

#define B_   32
#define TIN  16
#define X_   8192
#define H_   64
#define F_   128
#define K_   5
#define DEPTH 3
#define TOUT 32
#define TILE 128          // k_layer tile (4 waves x 32 rows)

typedef __attribute__((ext_vector_type(8))) _Float16 h16x8;
typedef __attribute__((ext_vector_type(4))) _Float16 h16x4;
typedef __attribute__((ext_vector_type(4))) float f32x4;

__device__ __forceinline__ float gelu_exact(float z) {
    return 0.5f * z * (1.0f + erff(z * 0.70710678118654752f));
}

// swizzled LDS address: row stride rb bytes, XOR (row&7)<<4 kills 128B-stride bank conflicts
__device__ __forceinline__ char* lp(void* base, int row, int cb, int rb) {
    return (char*)base + row * rb + (cb ^ ((row & 7) << 4));
}
// A-fragment (16x32 fp16) from swizzled LDS
__device__ __forceinline__ h16x8 lda(const void* base, int row, int kt, int rb, int lane) {
    return *(const h16x8*)((const char*)base + row * rb +
                           ((kt * 64 + ((lane >> 4) << 4)) ^ ((row & 7) << 4)));
}
// B-fragment from global weights W[N][K] fp16 row-major; kb = K*2 bytes
__device__ __forceinline__ h16x8 ldw(const _Float16* w, int nt, int kt, int kb, int lane) {
    return *(const h16x8*)((const char*)w + (nt * 16 + (lane & 15)) * kb +
                           kt * 64 + ((lane >> 4) << 4));
}

// ---------------- weight prep: fp32 -> fp16 in d_ws ----------------
__global__ __launch_bounds__(256) void k_prep_lin(const float* __restrict__ s,
                                                  _Float16* __restrict__ w, int n) {
    int i = blockIdx.x * 256 + threadIdx.x;
    if (i < n) w[i] = (_Float16)s[i];
}
// conv_w [3][64o][64d][5k] -> [3][5][64o][64d]
__global__ __launch_bounds__(256) void k_prep_conv(const float* __restrict__ s,
                                                   _Float16* __restrict__ w) {
    int t = blockIdx.x * 256 + threadIdx.x;
    if (t < DEPTH * 64 * 64 * K_) {
        int k = t % 5, d = (t / 5) % 64, o = (t / 320) % 64, i = t / 20480;
        w[((i * 5 + k) * 64 + o) * 64 + d] = (_Float16)s[t];
    }
}

// ---------------- encoder (runs once; fp32 VALU) ----------------
__global__ __launch_bounds__(256) void k_encoder(const float* __restrict__ xin,
                                                 const float* __restrict__ enc_w,
                                                 const float* __restrict__ enc_b,
                                                 float* __restrict__ psi) {
    const int b  = blockIdx.y;
    const int x0 = blockIdx.x * 64;
    __shared__ float s_x[TIN][64];
    __shared__ float s_w[TIN][H_];
    __shared__ float s_p[64][H_];
    const int tid = threadIdx.x;

    for (int idx = tid; idx < TIN * 64; idx += 256) {
        int t = idx >> 6, xl = idx & 63;
        s_x[t][xl] = xin[((size_t)b * TIN + t) * X_ + x0 + xl];
    }
    for (int idx = tid; idx < TIN * H_; idx += 256) {
        int t = idx >> 6, h = idx & 63;
        s_w[t][h] = enc_w[h * TIN + t];
    }
    __syncthreads();
    {
        int h = tid & 63, grp = tid >> 6;
        float bias = enc_b[h];
        for (int r = 0; r < 16; ++r) {
            int xl = grp * 16 + r;
            float acc = bias;
            #pragma unroll
            for (int t = 0; t < TIN; ++t) acc += s_x[t][xl] * s_w[t][h];
            s_p[xl][h] = acc;
        }
    }
    __syncthreads();
    {
        int lane = tid & 63, wv = tid >> 6;
        for (int r = 0; r < 16; ++r) {
            int xl = wv * 16 + r;
            float v = s_p[xl][lane];
            float s = v;
            #pragma unroll
            for (int off = 32; off; off >>= 1) s += __shfl_xor(s, off);
            float mu = s * (1.0f / 64.0f);
            float dv = v - mu;
            float q = dv * dv;
            #pragma unroll
            for (int off = 32; off; off >>= 1) q += __shfl_xor(q, off);
            float sd = sqrtf(q * (1.0f / 63.0f)) + 1e-6f;
            psi[((size_t)b * X_ + x0 + xl) * H_ + lane] = dv / sd;
        }
    }
}

// ---------------- fused layer, M=32/wave: conv -> MLP -> resid -> LN -> clip (-> dec head)
// LDS: sA (psi tile, 16.9KB) unioned with sM (mlp1 out, 32KB); sH separate (16KB). 48KB total.
__global__ __launch_bounds__(256, 3) void k_layer(const float* __restrict__ pin,
                                                  float* __restrict__ pout,
                                                  const _Float16* __restrict__ cw,  // [5][64][64]
                                                  const float* __restrict__ cb,
                                                  const _Float16* __restrict__ w1,  // [128][64]
                                                  const float* __restrict__ b1,
                                                  const _Float16* __restrict__ w2,  // [64][128]
                                                  const float* __restrict__ b2,
                                                  const float* __restrict__ g,
                                                  const float* __restrict__ bt,
                                                  const _Float16* __restrict__ d1,  // [64][64]
                                                  const float* __restrict__ b1d,
                                                  const float* __restrict__ w2d,
                                                  const float* __restrict__ b2d,
                                                  float* __restrict__ yout, int step) {
    __shared__ __align__(16) char smem[49152];
    _Float16* sA = (_Float16*)smem;            // 132 rows x 128B   (stage + conv phases)
    _Float16* sM = (_Float16*)smem;            // 128 rows x 256B   (after barrier 2; aliases sA)
    _Float16* sH = (_Float16*)(smem + 32768);  // 128 rows x 128B

    const int tid  = threadIdx.x;
    const int b    = blockIdx.y;
    const int x0   = blockIdx.x * TILE;
    const int lane = tid & 63, wv = tid >> 6;
    const int R0   = wv * 32;                // wave owns output rows [R0, R0+32)
    const int l15  = lane & 15, l4 = lane >> 4;

    // ---- stage psi rows [x0-2, x0+TILE+2) as swizzled fp16
    for (int idx = tid; idx < (TILE + 4) * 16; idx += 256) {
        int r = idx >> 4, c4 = idx & 15;
        int gx = x0 + r - 2;
        float4 v = make_float4(0.f, 0.f, 0.f, 0.f);
        if (gx >= 0 && gx < X_) v = *(const float4*)&pin[((size_t)b * X_ + gx) * H_ + c4 * 4];
        h16x4 hv;
        hv[0] = (_Float16)v.x; hv[1] = (_Float16)v.y;
        hv[2] = (_Float16)v.z; hv[3] = (_Float16)v.w;
        *(h16x4*)lp(sA, r, c4 * 8, 128) = hv;
    }
    __syncthreads();   // [1] sA fully staged

    // ---- conv: 5 shifted GEMMs, K=64; B-frags shared across 2 row-blocks
    f32x4 acc0[4], acc1[4];
    #pragma unroll
    for (int nt = 0; nt < 4; ++nt) {
        float bb = cb[nt * 16 + l15];
        acc0[nt] = (f32x4){bb, bb, bb, bb};
        acc1[nt] = acc0[nt];
    }
    #pragma unroll
    for (int k = 0; k < K_; ++k) {
        #pragma unroll
        for (int kt = 0; kt < 2; ++kt) {
            h16x8 a0 = lda(sA, R0 + l15 + k,      kt, 128, lane);
            h16x8 a1 = lda(sA, R0 + 16 + l15 + k, kt, 128, lane);
            #pragma unroll
            for (int nt = 0; nt < 4; ++nt) {
                h16x8 bf = ldw(cw + k * 4096, nt, kt, 128, lane);
                acc0[nt] = __builtin_amdgcn_mfma_f32_16x16x32_f16(a0, bf, acc0[nt], 0, 0, 0);
                acc1[nt] = __builtin_amdgcn_mfma_f32_16x16x32_f16(a1, bf, acc1[nt], 0, 0, 0);
            }
        }
    }
    #pragma unroll
    for (int nt = 0; nt < 4; ++nt) {
        int col = nt * 16 + l15;
        #pragma unroll
        for (int j = 0; j < 4; ++j) {
            int r0 = R0 + (l4 << 2) + j;
            *(_Float16*)lp(sH, r0,      col * 2, 128) = (_Float16)acc0[nt][j];
            *(_Float16*)lp(sH, r0 + 16, col * 2, 128) = (_Float16)acc1[nt][j];
        }
    }

    // ---- prefetch residual psi (fp32, L2-hot) into registers
    float res0[4][4], res1[4][4];   // [nt][j]
    #pragma unroll
    for (int j = 0; j < 4; ++j) {
        size_t g0 = ((size_t)b * X_ + x0 + R0 + (l4 << 2) + j) * H_;
        size_t g1 = g0 + 16 * H_;
        #pragma unroll
        for (int nt = 0; nt < 4; ++nt) {
            res0[nt][j] = pin[g0 + nt * 16 + l15];
            res1[nt][j] = pin[g1 + nt * 16 + l15];
        }
    }
    __syncthreads();   // [2] all conv sA reads done -> sM writes may alias sA

    // ---- mlp1: [64]->[128], gelu
    f32x4 m0[8], m1[8];
    #pragma unroll
    for (int nt = 0; nt < 8; ++nt) {
        float bb = b1[nt * 16 + l15];
        m0[nt] = (f32x4){bb, bb, bb, bb};
        m1[nt] = m0[nt];
    }
    #pragma unroll
    for (int kt = 0; kt < 2; ++kt) {
        h16x8 a0 = lda(sH, R0 + l15,      kt, 128, lane);
        h16x8 a1 = lda(sH, R0 + 16 + l15, kt, 128, lane);
        #pragma unroll
        for (int nt = 0; nt < 8; ++nt) {
            h16x8 bf = ldw(w1, nt, kt, 128, lane);
            m0[nt] = __builtin_amdgcn_mfma_f32_16x16x32_f16(a0, bf, m0[nt], 0, 0, 0);
            m1[nt] = __builtin_amdgcn_mfma_f32_16x16x32_f16(a1, bf, m1[nt], 0, 0, 0);
        }
    }
    #pragma unroll
    for (int nt = 0; nt < 8; ++nt) {
        int col = nt * 16 + l15;
        #pragma unroll
        for (int j = 0; j < 4; ++j) {
            int r0 = R0 + (l4 << 2) + j;
            *(_Float16*)lp(sM, r0,      col * 2, 256) = (_Float16)gelu_exact(m0[nt][j]);
            *(_Float16*)lp(sM, r0 + 16, col * 2, 256) = (_Float16)gelu_exact(m1[nt][j]);
        }
    }

    // ---- mlp2: [128]->[64]
    f32x4 o0[4], o1[4];
    #pragma unroll
    for (int nt = 0; nt < 4; ++nt) {
        float bb = b2[nt * 16 + l15];
        o0[nt] = (f32x4){bb, bb, bb, bb};
        o1[nt] = o0[nt];
    }
    #pragma unroll
    for (int kt = 0; kt < 4; ++kt) {
        h16x8 a0 = lda(sM, R0 + l15,      kt, 256, lane);
        h16x8 a1 = lda(sM, R0 + 16 + l15, kt, 256, lane);
        #pragma unroll
        for (int nt = 0; nt < 4; ++nt) {
            h16x8 bf = ldw(w2, nt, kt, 256, lane);
            o0[nt] = __builtin_amdgcn_mfma_f32_16x16x32_f16(a0, bf, o0[nt], 0, 0, 0);
            o1[nt] = __builtin_amdgcn_mfma_f32_16x16x32_f16(a1, bf, o1[nt], 0, 0, 0);
        }
    }

    // ---- residual + LN + clip + store (and stash fp16 psi_out in sH for dec head)
#define LN_BLOCK(OACC, RES, ROFF)                                              \
    {                                                                          \
        _Pragma("unroll")                                                      \
        for (int j = 0; j < 4; ++j) {                                          \
            int R = R0 + (ROFF) + (l4 << 2) + j;                               \
            size_t grow = ((size_t)b * X_ + x0 + R) * H_;                      \
            float v[4];                                                        \
            _Pragma("unroll")                                                  \
            for (int nt = 0; nt < 4; ++nt) v[nt] = OACC[nt][j] + RES[nt][j];   \
            float s = v[0] + v[1] + v[2] + v[3];                               \
            _Pragma("unroll")                                                  \
            for (int m = 1; m < 16; m <<= 1) s += __shfl_xor(s, m);            \
            float mu = s * (1.0f / 64.0f);                                     \
            float q = 0.f;                                                     \
            _Pragma("unroll")                                                  \
            for (int nt = 0; nt < 4; ++nt) { v[nt] -= mu; q += v[nt] * v[nt]; }\
            _Pragma("unroll")                                                  \
            for (int m = 1; m < 16; m <<= 1) q += __shfl_xor(q, m);            \
            float rs = rsqrtf(q * (1.0f / 64.0f) + 1e-5f);                     \
            _Pragma("unroll")                                                  \
            for (int nt = 0; nt < 4; ++nt) {                                   \
                int col = nt * 16 + l15;                                       \
                float o = v[nt] * rs * g[col] + bt[col];                       \
                o = fminf(10.0f, fmaxf(-10.0f, o));                            \
                pout[grow + col] = o;                                          \
                if (yout) *(_Float16*)lp(sH, R, col * 2, 128) = (_Float16)o;   \
            }                                                                  \
        }                                                                      \
    }
    LN_BLOCK(o0, res0, 0)
    LN_BLOCK(o1, res1, 16)
#undef LN_BLOCK

    // ---- fused decoder head (depth 2 only): y = gelu(psi@d1^T+b1d)@w2d + b2d
    if (yout) {
        f32x4 d0[4], dd1[4];
        #pragma unroll
        for (int nt = 0; nt < 4; ++nt) {
            float bb = b1d[nt * 16 + l15];
            d0[nt] = (f32x4){bb, bb, bb, bb};
            dd1[nt] = d0[nt];
        }
        #pragma unroll
        for (int kt = 0; kt < 2; ++kt) {
            h16x8 a0 = lda(sH, R0 + l15,      kt, 128, lane);
            h16x8 a1 = lda(sH, R0 + 16 + l15, kt, 128, lane);
            #pragma unroll
            for (int nt = 0; nt < 4; ++nt) {
                h16x8 bf = ldw(d1, nt, kt, 128, lane);
                d0[nt]  = __builtin_amdgcn_mfma_f32_16x16x32_f16(a0, bf, d0[nt], 0, 0, 0);
                dd1[nt] = __builtin_amdgcn_mfma_f32_16x16x32_f16(a1, bf, dd1[nt], 0, 0, 0);
            }
        }
        float w2v[4];
        #pragma unroll
        for (int nt = 0; nt < 4; ++nt) w2v[nt] = w2d[nt * 16 + l15];
        float bb = b2d[0];
        size_t ybase = ((size_t)b * TOUT + step) * X_ + x0;
        #pragma unroll
        for (int j = 0; j < 4; ++j) {
            float s0 = 0.f, s1 = 0.f;
            #pragma unroll
            for (int nt = 0; nt < 4; ++nt) {
                s0 += gelu_exact(d0[nt][j])  * w2v[nt];
                s1 += gelu_exact(dd1[nt][j]) * w2v[nt];
            }
            #pragma unroll
            for (int m = 1; m < 16; m <<= 1) { s0 += __shfl_xor(s0, m); s1 += __shfl_xor(s1, m); }
            if (l15 == 0) {
                int R = R0 + (l4 << 2) + j;
                yout[ybase + R]      = s0 + bb;
                yout[ybase + R + 16] = s1 + bb;
            }
        }
    }
}

extern "C" void kernel_launch(void* const* d_in, const int* in_sizes, int n_in,
                              void* d_out, int out_size, void* d_ws, size_t ws_size,
                              hipStream_t stream) {
    const float* xin    = (const float*)d_in[0];
    const float* enc_w  = (const float*)d_in[1];
    const float* enc_b  = (const float*)d_in[2];
    const float* conv_w = (const float*)d_in[3];
    const float* conv_b = (const float*)d_in[4];
    const float* mlp_w1 = (const float*)d_in[5];
    const float* mlp_b1 = (const float*)d_in[6];
    const float* mlp_w2 = (const float*)d_in[7];
    const float* mlp_b2 = (const float*)d_in[8];
    const float* ln_g   = (const float*)d_in[9];
    const float* ln_b   = (const float*)d_in[10];
    const float* dec_w1 = (const float*)d_in[11];
    const float* dec_b1 = (const float*)d_in[12];
    const float* dec_w2 = (const float*)d_in[13];
    const float* dec_b2 = (const float*)d_in[14];
    float* out = (float*)d_out;

    const size_t PSI = (size_t)B_ * X_ * H_;
    float* psiA = (float*)d_ws;
    float* psiB = psiA + PSI;
    _Float16* cwf = (_Float16*)(psiB + PSI);  // [3][5][64][64]
    _Float16* w1f = cwf + 61440;              // [3][128][64]
    _Float16* w2f = w1f + 24576;              // [3][64][128]
    _Float16* d1f = w2f + 24576;              // [64][64]
    (void)ws_size; (void)n_in; (void)in_sizes; (void)out_size;

    k_prep_conv<<<240, 256, 0, stream>>>(conv_w, cwf);
    k_prep_lin<<<96, 256, 0, stream>>>(mlp_w1, w1f, 24576);
    k_prep_lin<<<96, 256, 0, stream>>>(mlp_w2, w2f, 24576);
    k_prep_lin<<<16, 256, 0, stream>>>(dec_w1, d1f, 4096);

    k_encoder<<<dim3(X_ / 64, B_), 256, 0, stream>>>(xin, enc_w, enc_b, psiA);

    const float* cur = psiA;
    float* nxt = psiB;
    for (int t = 0; t < TOUT; ++t) {
        for (int i = 0; i < DEPTH; ++i) {
            float* yout = (i == DEPTH - 1) ? out : nullptr;
            k_layer<<<dim3(X_ / TILE, B_), 256, 0, stream>>>(
                cur, nxt,
                cwf + i * 20480, conv_b + i * H_,
                w1f + i * 8192,  mlp_b1 + i * F_,
                w2f + i * 8192,  mlp_b2 + i * H_,
                ln_g + i * H_, ln_b + i * H_,
                d1f, dec_b1, dec_w2, dec_b2, yout, t);
            float* tmp = (float*)cur; cur = nxt; nxt = tmp;
        }
    }
}

// Round 6
// 10302.219 us; speedup vs baseline: 1.0984x; 1.0984x over previous
//
#include <hip/hip_runtime.h>
#include <hip/hip_bf16.h>

#define B_   32
#define TIN  16
#define X_   8192
#define H_   64
#define F_   128
#define K_   5
#define DEPTH 3
#define TOUT 32
#define TILE 128          // k_layer tile (4 waves x 32 rows)

typedef __attribute__((ext_vector_type(8))) _Float16 h16x8;
typedef __attribute__((ext_vector_type(4))) _Float16 h16x4;
typedef __attribute__((ext_vector_type(4))) float f32x4;

// exact-enough GELU: erf via Abramowitz-Stegun 7.1.26 (|eps| <= 1.5e-7), branch-free
__device__ __forceinline__ float gelu_fast(float z) {
    float t = fminf(fabsf(z) * 0.70710678118654752f, 3.9192f);  // erf(3.92)=1-3e-8
    float w = __builtin_amdgcn_rcpf(1.0f + 0.3275911f * t);     // 1 ulp rcp
    float p = w * (0.254829592f + w * (-0.284496736f + w * (1.421413741f +
              w * (-1.453152027f + w * 1.061405429f))));
    float e = __expf(-t * t);                                    // native exp
    float erf_abs = 1.0f - p * e;
    float erf_z = copysignf(erf_abs, z);
    return 0.5f * z * (1.0f + erf_z);
}

// swizzled LDS address: row stride rb bytes, XOR (row&7)<<4 kills 128B-stride bank conflicts
__device__ __forceinline__ char* lp(void* base, int row, int cb, int rb) {
    return (char*)base + row * rb + (cb ^ ((row & 7) << 4));
}
// A-fragment (16x32 fp16) from swizzled LDS
__device__ __forceinline__ h16x8 lda(const void* base, int row, int kt, int rb, int lane) {
    return *(const h16x8*)((const char*)base + row * rb +
                           ((kt * 64 + ((lane >> 4) << 4)) ^ ((row & 7) << 4)));
}
// B-fragment from global weights W[N][K] fp16 row-major; kb = K*2 bytes
__device__ __forceinline__ h16x8 ldw(const _Float16* w, int nt, int kt, int kb, int lane) {
    return *(const h16x8*)((const char*)w + (nt * 16 + (lane & 15)) * kb +
                           kt * 64 + ((lane >> 4) << 4));
}

// ---------------- weight prep: fp32 -> fp16 in d_ws ----------------
__global__ __launch_bounds__(256) void k_prep_lin(const float* __restrict__ s,
                                                  _Float16* __restrict__ w, int n) {
    int i = blockIdx.x * 256 + threadIdx.x;
    if (i < n) w[i] = (_Float16)s[i];
}
// conv_w [3][64o][64d][5k] -> [3][5][64o][64d]
__global__ __launch_bounds__(256) void k_prep_conv(const float* __restrict__ s,
                                                   _Float16* __restrict__ w) {
    int t = blockIdx.x * 256 + threadIdx.x;
    if (t < DEPTH * 64 * 64 * K_) {
        int k = t % 5, d = (t / 5) % 64, o = (t / 320) % 64, i = t / 20480;
        w[((i * 5 + k) * 64 + o) * 64 + d] = (_Float16)s[t];
    }
}

// ---------------- encoder (runs once; fp32 VALU) ----------------
__global__ __launch_bounds__(256) void k_encoder(const float* __restrict__ xin,
                                                 const float* __restrict__ enc_w,
                                                 const float* __restrict__ enc_b,
                                                 float* __restrict__ psi) {
    const int b  = blockIdx.y;
    const int x0 = blockIdx.x * 64;
    __shared__ float s_x[TIN][64];
    __shared__ float s_w[TIN][H_];
    __shared__ float s_p[64][H_];
    const int tid = threadIdx.x;

    for (int idx = tid; idx < TIN * 64; idx += 256) {
        int t = idx >> 6, xl = idx & 63;
        s_x[t][xl] = xin[((size_t)b * TIN + t) * X_ + x0 + xl];
    }
    for (int idx = tid; idx < TIN * H_; idx += 256) {
        int t = idx >> 6, h = idx & 63;
        s_w[t][h] = enc_w[h * TIN + t];
    }
    __syncthreads();
    {
        int h = tid & 63, grp = tid >> 6;
        float bias = enc_b[h];
        for (int r = 0; r < 16; ++r) {
            int xl = grp * 16 + r;
            float acc = bias;
            #pragma unroll
            for (int t = 0; t < TIN; ++t) acc += s_x[t][xl] * s_w[t][h];
            s_p[xl][h] = acc;
        }
    }
    __syncthreads();
    {
        int lane = tid & 63, wv = tid >> 6;
        for (int r = 0; r < 16; ++r) {
            int xl = wv * 16 + r;
            float v = s_p[xl][lane];
            float s = v;
            #pragma unroll
            for (int off = 32; off; off >>= 1) s += __shfl_xor(s, off);
            float mu = s * (1.0f / 64.0f);
            float dv = v - mu;
            float q = dv * dv;
            #pragma unroll
            for (int off = 32; off; off >>= 1) q += __shfl_xor(q, off);
            float sd = sqrtf(q * (1.0f / 63.0f)) + 1e-6f;
            psi[((size_t)b * X_ + x0 + xl) * H_ + lane] = dv / sd;
        }
    }
}

// ---------------- fused layer, M=32/wave: conv -> MLP -> resid -> LN -> clip (-> dec head)
// wave-private after ONE barrier; separate sA/sH/sM (66KB, 2 blocks/CU, VGPR cap 256)
__global__ __launch_bounds__(256, 2) void k_layer(const float* __restrict__ pin,
                                                  float* __restrict__ pout,
                                                  const _Float16* __restrict__ cw,  // [5][64][64]
                                                  const float* __restrict__ cb,
                                                  const _Float16* __restrict__ w1,  // [128][64]
                                                  const float* __restrict__ b1,
                                                  const _Float16* __restrict__ w2,  // [64][128]
                                                  const float* __restrict__ b2,
                                                  const float* __restrict__ g,
                                                  const float* __restrict__ bt,
                                                  const _Float16* __restrict__ d1,  // [64][64]
                                                  const float* __restrict__ b1d,
                                                  const float* __restrict__ w2d,
                                                  const float* __restrict__ b2d,
                                                  float* __restrict__ yout, int step) {
    __shared__ __align__(16) _Float16 sA[(TILE + 4) * 64];   // psi tile + halo (132 rows)
    __shared__ __align__(16) _Float16 sH[TILE * 64];         // conv out / psi_out stash
    __shared__ __align__(16) _Float16 sM[TILE * 128];        // mlp1 out (gelu'd)

    const int tid  = threadIdx.x;
    const int b    = blockIdx.y;
    const int x0   = blockIdx.x * TILE;
    const int lane = tid & 63, wv = tid >> 6;
    const int R0   = wv * 32;                // wave owns output rows [R0, R0+32)
    const int l15  = lane & 15, l4 = lane >> 4;

    // ---- stage psi rows [x0-2, x0+TILE+2) as swizzled fp16
    for (int idx = tid; idx < (TILE + 4) * 16; idx += 256) {
        int r = idx >> 4, c4 = idx & 15;
        int gx = x0 + r - 2;
        float4 v = make_float4(0.f, 0.f, 0.f, 0.f);
        if (gx >= 0 && gx < X_) v = *(const float4*)&pin[((size_t)b * X_ + gx) * H_ + c4 * 4];
        h16x4 hv;
        hv[0] = (_Float16)v.x; hv[1] = (_Float16)v.y;
        hv[2] = (_Float16)v.z; hv[3] = (_Float16)v.w;
        *(h16x4*)lp(sA, r, c4 * 8, 128) = hv;
    }
    __syncthreads();   // the ONLY barrier; everything below is wave-private

    // ---- conv: 5 shifted GEMMs, K=64; B-frags grouped per-k so scheduler hoists next k
    f32x4 acc0[4], acc1[4];
    #pragma unroll
    for (int nt = 0; nt < 4; ++nt) {
        float bb = cb[nt * 16 + l15];
        acc0[nt] = (f32x4){bb, bb, bb, bb};
        acc1[nt] = acc0[nt];
    }
    #pragma unroll
    for (int k = 0; k < K_; ++k) {
        h16x8 bf0[4], bf1[4];
        #pragma unroll
        for (int nt = 0; nt < 4; ++nt) {
            bf0[nt] = ldw(cw + k * 4096, nt, 0, 128, lane);
            bf1[nt] = ldw(cw + k * 4096, nt, 1, 128, lane);
        }
        h16x8 a00 = lda(sA, R0 + l15 + k,      0, 128, lane);
        h16x8 a01 = lda(sA, R0 + 16 + l15 + k, 0, 128, lane);
        h16x8 a10 = lda(sA, R0 + l15 + k,      1, 128, lane);
        h16x8 a11 = lda(sA, R0 + 16 + l15 + k, 1, 128, lane);
        #pragma unroll
        for (int nt = 0; nt < 4; ++nt) {
            acc0[nt] = __builtin_amdgcn_mfma_f32_16x16x32_f16(a00, bf0[nt], acc0[nt], 0, 0, 0);
            acc1[nt] = __builtin_amdgcn_mfma_f32_16x16x32_f16(a01, bf0[nt], acc1[nt], 0, 0, 0);
        }
        #pragma unroll
        for (int nt = 0; nt < 4; ++nt) {
            acc0[nt] = __builtin_amdgcn_mfma_f32_16x16x32_f16(a10, bf1[nt], acc0[nt], 0, 0, 0);
            acc1[nt] = __builtin_amdgcn_mfma_f32_16x16x32_f16(a11, bf1[nt], acc1[nt], 0, 0, 0);
        }
    }
    #pragma unroll
    for (int nt = 0; nt < 4; ++nt) {
        int col = nt * 16 + l15;
        #pragma unroll
        for (int j = 0; j < 4; ++j) {
            int r0 = R0 + (l4 << 2) + j;
            *(_Float16*)lp(sH, r0,      col * 2, 128) = (_Float16)acc0[nt][j];
            *(_Float16*)lp(sH, r0 + 16, col * 2, 128) = (_Float16)acc1[nt][j];
        }
    }

    // ---- mlp1: [64]->[128]; preload ALL 16 B-frags (64 VGPR) to kill per-kt stalls
    {
        h16x8 bw[2][8];
        #pragma unroll
        for (int kt = 0; kt < 2; ++kt)
            #pragma unroll
            for (int nt = 0; nt < 8; ++nt) bw[kt][nt] = ldw(w1, nt, kt, 128, lane);

        f32x4 m0[8], m1[8];
        #pragma unroll
        for (int nt = 0; nt < 8; ++nt) {
            float bb = b1[nt * 16 + l15];
            m0[nt] = (f32x4){bb, bb, bb, bb};
            m1[nt] = m0[nt];
        }
        #pragma unroll
        for (int kt = 0; kt < 2; ++kt) {
            h16x8 a0 = lda(sH, R0 + l15,      kt, 128, lane);
            h16x8 a1 = lda(sH, R0 + 16 + l15, kt, 128, lane);
            #pragma unroll
            for (int nt = 0; nt < 8; ++nt) {
                m0[nt] = __builtin_amdgcn_mfma_f32_16x16x32_f16(a0, bw[kt][nt], m0[nt], 0, 0, 0);
                m1[nt] = __builtin_amdgcn_mfma_f32_16x16x32_f16(a1, bw[kt][nt], m1[nt], 0, 0, 0);
            }
        }
        #pragma unroll
        for (int nt = 0; nt < 8; ++nt) {
            int col = nt * 16 + l15;
            #pragma unroll
            for (int j = 0; j < 4; ++j) {
                int r0 = R0 + (l4 << 2) + j;
                *(_Float16*)lp(sM, r0,      col * 2, 256) = (_Float16)gelu_fast(m0[nt][j]);
                *(_Float16*)lp(sM, r0 + 16, col * 2, 256) = (_Float16)gelu_fast(m1[nt][j]);
            }
        }
    }

    // ---- residual prefetch (overlaps mlp2 MFMAs)
    float res0[4][4], res1[4][4];   // [nt][j]
    #pragma unroll
    for (int j = 0; j < 4; ++j) {
        size_t g0 = ((size_t)b * X_ + x0 + R0 + (l4 << 2) + j) * H_;
        size_t g1 = g0 + 16 * H_;
        #pragma unroll
        for (int nt = 0; nt < 4; ++nt) {
            res0[nt][j] = pin[g0 + nt * 16 + l15];
            res1[nt][j] = pin[g1 + nt * 16 + l15];
        }
    }

    // ---- mlp2: [128]->[64]; preload ALL 16 B-frags
    f32x4 o0[4], o1[4];
    {
        h16x8 bw[4][4];
        #pragma unroll
        for (int kt = 0; kt < 4; ++kt)
            #pragma unroll
            for (int nt = 0; nt < 4; ++nt) bw[kt][nt] = ldw(w2, nt, kt, 256, lane);

        #pragma unroll
        for (int nt = 0; nt < 4; ++nt) {
            float bb = b2[nt * 16 + l15];
            o0[nt] = (f32x4){bb, bb, bb, bb};
            o1[nt] = o0[nt];
        }
        #pragma unroll
        for (int kt = 0; kt < 4; ++kt) {
            h16x8 a0 = lda(sM, R0 + l15,      kt, 256, lane);
            h16x8 a1 = lda(sM, R0 + 16 + l15, kt, 256, lane);
            #pragma unroll
            for (int nt = 0; nt < 4; ++nt) {
                o0[nt] = __builtin_amdgcn_mfma_f32_16x16x32_f16(a0, bw[kt][nt], o0[nt], 0, 0, 0);
                o1[nt] = __builtin_amdgcn_mfma_f32_16x16x32_f16(a1, bw[kt][nt], o1[nt], 0, 0, 0);
            }
        }
    }

    // ---- residual + LN + clip + store (and stash fp16 psi_out in sH for dec head)
#define LN_BLOCK(OACC, RES, ROFF)                                              \
    {                                                                          \
        _Pragma("unroll")                                                      \
        for (int j = 0; j < 4; ++j) {                                          \
            int R = R0 + (ROFF) + (l4 << 2) + j;                               \
            size_t grow = ((size_t)b * X_ + x0 + R) * H_;                      \
            float v[4];                                                        \
            _Pragma("unroll")                                                  \
            for (int nt = 0; nt < 4; ++nt) v[nt] = OACC[nt][j] + RES[nt][j];   \
            float s = v[0] + v[1] + v[2] + v[3];                               \
            _Pragma("unroll")                                                  \
            for (int m = 1; m < 16; m <<= 1) s += __shfl_xor(s, m);            \
            float mu = s * (1.0f / 64.0f);                                     \
            float q = 0.f;                                                     \
            _Pragma("unroll")                                                  \
            for (int nt = 0; nt < 4; ++nt) { v[nt] -= mu; q += v[nt] * v[nt]; }\
            _Pragma("unroll")                                                  \
            for (int m = 1; m < 16; m <<= 1) q += __shfl_xor(q, m);            \
            float rs = rsqrtf(q * (1.0f / 64.0f) + 1e-5f);                     \
            _Pragma("unroll")                                                  \
            for (int nt = 0; nt < 4; ++nt) {                                   \
                int col = nt * 16 + l15;                                       \
                float o = v[nt] * rs * g[col] + bt[col];                       \
                o = fminf(10.0f, fmaxf(-10.0f, o));                            \
                pout[grow + col] = o;                                          \
                if (yout) *(_Float16*)lp(sH, R, col * 2, 128) = (_Float16)o;   \
            }                                                                  \
        }                                                                      \
    }
    LN_BLOCK(o0, res0, 0)
    LN_BLOCK(o1, res1, 16)
#undef LN_BLOCK

    // ---- fused decoder head (depth 2 only): y = gelu(psi@d1^T+b1d)@w2d + b2d
    if (yout) {
        h16x8 bw[2][4];
        #pragma unroll
        for (int kt = 0; kt < 2; ++kt)
            #pragma unroll
            for (int nt = 0; nt < 4; ++nt) bw[kt][nt] = ldw(d1, nt, kt, 128, lane);

        f32x4 d0[4], dd1[4];
        #pragma unroll
        for (int nt = 0; nt < 4; ++nt) {
            float bb = b1d[nt * 16 + l15];
            d0[nt] = (f32x4){bb, bb, bb, bb};
            dd1[nt] = d0[nt];
        }
        #pragma unroll
        for (int kt = 0; kt < 2; ++kt) {
            h16x8 a0 = lda(sH, R0 + l15,      kt, 128, lane);
            h16x8 a1 = lda(sH, R0 + 16 + l15, kt, 128, lane);
            #pragma unroll
            for (int nt = 0; nt < 4; ++nt) {
                d0[nt]  = __builtin_amdgcn_mfma_f32_16x16x32_f16(a0, bw[kt][nt], d0[nt], 0, 0, 0);
                dd1[nt] = __builtin_amdgcn_mfma_f32_16x16x32_f16(a1, bw[kt][nt], dd1[nt], 0, 0, 0);
            }
        }
        float w2v[4];
        #pragma unroll
        for (int nt = 0; nt < 4; ++nt) w2v[nt] = w2d[nt * 16 + l15];
        float bb = b2d[0];
        size_t ybase = ((size_t)b * TOUT + step) * X_ + x0;
        #pragma unroll
        for (int j = 0; j < 4; ++j) {
            float s0 = 0.f, s1 = 0.f;
            #pragma unroll
            for (int nt = 0; nt < 4; ++nt) {
                s0 += gelu_fast(d0[nt][j])  * w2v[nt];
                s1 += gelu_fast(dd1[nt][j]) * w2v[nt];
            }
            #pragma unroll
            for (int m = 1; m < 16; m <<= 1) { s0 += __shfl_xor(s0, m); s1 += __shfl_xor(s1, m); }
            if (l15 == 0) {
                int R = R0 + (l4 << 2) + j;
                yout[ybase + R]      = s0 + bb;
                yout[ybase + R + 16] = s1 + bb;
            }
        }
    }
}

extern "C" void kernel_launch(void* const* d_in, const int* in_sizes, int n_in,
                              void* d_out, int out_size, void* d_ws, size_t ws_size,
                              hipStream_t stream) {
    const float* xin    = (const float*)d_in[0];
    const float* enc_w  = (const float*)d_in[1];
    const float* enc_b  = (const float*)d_in[2];
    const float* conv_w = (const float*)d_in[3];
    const float* conv_b = (const float*)d_in[4];
    const float* mlp_w1 = (const float*)d_in[5];
    const float* mlp_b1 = (const float*)d_in[6];
    const float* mlp_w2 = (const float*)d_in[7];
    const float* mlp_b2 = (const float*)d_in[8];
    const float* ln_g   = (const float*)d_in[9];
    const float* ln_b   = (const float*)d_in[10];
    const float* dec_w1 = (const float*)d_in[11];
    const float* dec_b1 = (const float*)d_in[12];
    const float* dec_w2 = (const float*)d_in[13];
    const float* dec_b2 = (const float*)d_in[14];
    float* out = (float*)d_out;

    const size_t PSI = (size_t)B_ * X_ * H_;
    float* psiA = (float*)d_ws;
    float* psiB = psiA + PSI;
    _Float16* cwf = (_Float16*)(psiB + PSI);  // [3][5][64][64]
    _Float16* w1f = cwf + 61440;              // [3][128][64]
    _Float16* w2f = w1f + 24576;              // [3][64][128]
    _Float16* d1f = w2f + 24576;              // [64][64]
    (void)ws_size; (void)n_in; (void)in_sizes; (void)out_size;

    k_prep_conv<<<240, 256, 0, stream>>>(conv_w, cwf);
    k_prep_lin<<<96, 256, 0, stream>>>(mlp_w1, w1f, 24576);
    k_prep_lin<<<96, 256, 0, stream>>>(mlp_w2, w2f, 24576);
    k_prep_lin<<<16, 256, 0, stream>>>(dec_w1, d1f, 4096);

    k_encoder<<<dim3(X_ / 64, B_), 256, 0, stream>>>(xin, enc_w, enc_b, psiA);

    const float* cur = psiA;
    float* nxt = psiB;
    for (int t = 0; t < TOUT; ++t) {
        for (int i = 0; i < DEPTH; ++i) {
            float* yout = (i == DEPTH - 1) ? out : nullptr;
            k_layer<<<dim3(X_ / TILE, B_), 256, 0, stream>>>(
                cur, nxt,
                cwf + i * 20480, conv_b + i * H_,
                w1f + i * 8192,  mlp_b1 + i * F_,
                w2f + i * 8192,  mlp_b2 + i * H_,
                ln_g + i * H_, ln_b + i * H_,
                d1f, dec_b1, dec_w2, dec_b2, yout, t);
            float* tmp = (float*)cur; cur = nxt; nxt = tmp;
        }
    }
}